// Round 4
// baseline (122.785 us; speedup 1.0000x reference)
//
#include <hip/hip_runtime.h>

// Problem constants (match the reference file).
constexpr int DIM = 512;   // irreps dim for x, y, out
constexpr int C   = 16;    // channel multiplicity
constexpr int TPB = 1024;  // threads per block (16 waves)

// Setup (one launch, tiny):
//   block 0:   start[d] for d in [0,DIM] (binary search on sorted index_out),
//              segment lengths, rank d's by (length desc, d) and emit
//              plan[rank] = {seg_start, seg_end, d*C, 0}.
//   blocks>=1: pack pdata[p] = {i1*C, i2*C, scale_bits, 0}.
__global__ void setup_kernel(const int* __restrict__ io,
                             const int* __restrict__ i1,
                             const int* __restrict__ i2,
                             const float* __restrict__ scale,
                             int4* __restrict__ plan,
                             int4* __restrict__ pdata,
                             int nnz) {
    if (blockIdx.x == 0) {
        __shared__ int s_start[DIM + 1];
        __shared__ int s_len[DIM];
        for (int d = threadIdx.x; d <= DIM; d += blockDim.x) {
            int lo = 0, hi = nnz;
            while (lo < hi) {
                int mid = (lo + hi) >> 1;
                if (io[mid] < d) lo = mid + 1; else hi = mid;
            }
            s_start[d] = lo;
        }
        __syncthreads();
        for (int d = threadIdx.x; d < DIM; d += blockDim.x)
            s_len[d] = s_start[d + 1] - s_start[d];
        __syncthreads();
        for (int d = threadIdx.x; d < DIM; d += blockDim.x) {
            const int ld = s_len[d];
            int rank = 0;
            for (int j = 0; j < DIM; ++j) {
                const int lj = s_len[j];
                rank += (lj > ld) || (lj == ld && j < d);
            }
            plan[rank] = make_int4(s_start[d], s_start[d + 1], d * C, 0);
        }
    } else {
        const int t = (blockIdx.x - 1) * blockDim.x + threadIdx.x;
        if (t < nnz)
            pdata[t] = make_int4(i1[t] * C, i2[t] * C, __float_as_int(scale[t]), 0);
    }
}

// One block per n. Stage x-row and y-row in LDS (LINEAR layout — R3's swizzle
// regressed 8x on conflicts). Each thread owns (rank, c-quad): segment lengths
// are near-equal across a wave, so divergence waste ~ eliminated. 1-deep
// software pipeline over the segment. No atomics; each output written once.
__global__ __launch_bounds__(TPB) void tp_lds_kernel(
    const float* __restrict__ x, const float* __restrict__ y,
    const int4* __restrict__ plan,
    const int4* __restrict__ pdata,
    float* __restrict__ out) {
    __shared__ float xs[DIM * C];   // 32 KiB
    __shared__ float ys[DIM * C];   // 32 KiB -> 64 KiB total, 2 blocks/CU

    const int n = blockIdx.x;
    const float4* __restrict__ xr = reinterpret_cast<const float4*>(x + (size_t)n * (DIM * C));
    const float4* __restrict__ yr = reinterpret_cast<const float4*>(y + (size_t)n * (DIM * C));
    float4* xs4 = reinterpret_cast<float4*>(xs);
    float4* ys4 = reinterpret_cast<float4*>(ys);

    #pragma unroll
    for (int i = threadIdx.x; i < DIM * C / 4; i += TPB) {
        xs4[i] = xr[i];
        ys4[i] = yr[i];
    }
    __syncthreads();

    const int c4   = (threadIdx.x & 3) << 2;  // channel quad offset: 0,4,8,12
    const int dloc = threadIdx.x >> 2;        // 0..255, rank index
    float* __restrict__ orow = out + (size_t)n * (DIM * C);

    #pragma unroll
    for (int db = 0; db < DIM; db += TPB / 4) {   // 2 iterations
        const int4 pl = plan[db + dloc];
        const int s = pl.x;
        const int e = pl.y;
        float ax = 0.f, ay = 0.f, az = 0.f, aw = 0.f;
        int p = s;
        if (p < e) {
            int4   pd = pdata[p];
            float4 xv = *reinterpret_cast<const float4*>(xs + pd.x + c4);
            float4 yv = *reinterpret_cast<const float4*>(ys + pd.y + c4);
            while (++p < e) {
                // issue next path's loads before consuming current
                const int4   pdn = pdata[p];
                const float4 xvn = *reinterpret_cast<const float4*>(xs + pdn.x + c4);
                const float4 yvn = *reinterpret_cast<const float4*>(ys + pdn.y + c4);
                const float sc = __int_as_float(pd.z);
                ax = fmaf(sc * xv.x, yv.x, ax);
                ay = fmaf(sc * xv.y, yv.y, ay);
                az = fmaf(sc * xv.z, yv.z, az);
                aw = fmaf(sc * xv.w, yv.w, aw);
                pd = pdn; xv = xvn; yv = yvn;
            }
            const float sc = __int_as_float(pd.z);
            ax = fmaf(sc * xv.x, yv.x, ax);
            ay = fmaf(sc * xv.y, yv.y, ay);
            az = fmaf(sc * xv.z, yv.z, az);
            aw = fmaf(sc * xv.w, yv.w, aw);
        }
        *reinterpret_cast<float4*>(orow + pl.z + c4) = make_float4(ax, ay, az, aw);
    }
}

extern "C" void kernel_launch(void* const* d_in, const int* in_sizes, int n_in,
                              void* d_out, int out_size, void* d_ws, size_t ws_size,
                              hipStream_t stream) {
    const float* x     = (const float*)d_in[0];
    const float* y     = (const float*)d_in[1];
    const float* scale = (const float*)d_in[2];
    const int*   i1    = (const int*)d_in[3];
    const int*   i2    = (const int*)d_in[4];
    const int*   io    = (const int*)d_in[5];
    float* out = (float*)d_out;

    const int nnz = in_sizes[2];
    const int N   = in_sizes[0] / (DIM * C);

    int4* plan  = (int4*)d_ws;                       // DIM int4s (8 KiB)
    int4* pdata = (int4*)((char*)d_ws + 8192);       // nnz int4s (64 KiB)

    const int pack_blocks = (nnz + 255) / 256;
    setup_kernel<<<1 + pack_blocks, 256, 0, stream>>>(io, i1, i2, scale, plan, pdata, nnz);
    tp_lds_kernel<<<N, TPB, 0, stream>>>(x, y, plan, pdata, out);
}

// Round 5
// 103.551 us; speedup vs baseline: 1.1857x; 1.1857x over previous
//
#include <hip/hip_runtime.h>

// Problem constants (match the reference file).
constexpr int DIM = 512;   // irreps dim for x, y, out
constexpr int C   = 16;    // channel multiplicity
constexpr int TPB = 1024;  // threads per block (16 waves)
constexpr int NPB = 2;     // n's (batch rows) per block
constexpr int GROUPS = TPB / 8;            // 128 8-lane groups per block
constexpr int LDSF = DIM * NPB * C;        // 16384 floats (64 KiB) per array

// Setup (one launch):
//   block 0:   start[d] via binary search on sorted index_out; rank d's by
//              (segment length desc, d); plan[rank] = {start, end, d*C, 0}.
//   blocks>=1: pdata[p] = {i1*NPB*C, i2*NPB*C, scale_bits, 0}
//              (float offsets of the interleaved row-pair in LDS).
__global__ void setup_kernel(const int* __restrict__ io,
                             const int* __restrict__ i1,
                             const int* __restrict__ i2,
                             const float* __restrict__ scale,
                             int4* __restrict__ plan,
                             int4* __restrict__ pdata,
                             int nnz) {
    if (blockIdx.x == 0) {
        __shared__ int s_start[DIM + 1];
        __shared__ int s_len[DIM];
        for (int d = threadIdx.x; d <= DIM; d += blockDim.x) {
            int lo = 0, hi = nnz;
            while (lo < hi) {
                int mid = (lo + hi) >> 1;
                if (io[mid] < d) lo = mid + 1; else hi = mid;
            }
            s_start[d] = lo;
        }
        __syncthreads();
        for (int d = threadIdx.x; d < DIM; d += blockDim.x)
            s_len[d] = s_start[d + 1] - s_start[d];
        __syncthreads();
        for (int d = threadIdx.x; d < DIM; d += blockDim.x) {
            const int ld = s_len[d];
            int rank = 0;
            for (int j = 0; j < DIM; ++j) {
                const int lj = s_len[j];
                rank += (lj > ld) || (lj == ld && j < d);
            }
            plan[rank] = make_int4(s_start[d], s_start[d + 1], d * C, 0);
        }
    } else {
        const int t = (blockIdx.x - 1) * blockDim.x + threadIdx.x;
        if (t < nnz)
            pdata[t] = make_int4(i1[t] * (NPB * C), i2[t] * (NPB * C),
                                 __float_as_int(scale[t]), 0);
    }
}

// One block per PAIR of n. LDS holds X[a][n2][c] and Y[a][n2][c] (row-pair =
// 128 B, 128 B-aligned -> every gathered row spans all 32 banks exactly once;
// 8 groups/wave -> every bank serves exactly 8 distinct addresses per
// ds_read_b128 = the stride-1 baseline profile, for ANY random rows).
// Each 8-lane group owns output d's (balanced by plan rank); lane = (n, c4).
__global__ __launch_bounds__(TPB) void tp_kernel(
    const float* __restrict__ x, const float* __restrict__ y,
    const int4* __restrict__ plan,
    const int4* __restrict__ pdata,
    float* __restrict__ out) {
    extern __shared__ float lds[];
    float* xs = lds;            // LDSF floats
    float* ys = lds + LDSF;     // LDSF floats

    const int n0 = blockIdx.x * NPB;
    const float4* __restrict__ xg = reinterpret_cast<const float4*>(x);
    const float4* __restrict__ yg = reinterpret_cast<const float4*>(y);
    float4* xs4 = reinterpret_cast<float4*>(xs);
    float4* ys4 = reinterpret_cast<float4*>(ys);

    // Staging: LDS float4-slot s <-> (a = s>>3, n = (s>>2)&1, cq = s&3).
    // Global float4 index = (n0+n)*(DIM*C/4) + a*4 + cq.  Coalesced in 64 B
    // chunks; LDS writes perfectly linear.
    #pragma unroll
    for (int s = threadIdx.x; s < LDSF / 4; s += TPB) {
        const int a = s >> 3, n = (s >> 2) & 1, cq = s & 3;
        const size_t g = (size_t)(n0 + n) * (DIM * C / 4) + a * 4 + cq;
        xs4[s] = xg[g];
        ys4[s] = yg[g];
    }
    __syncthreads();

    const int lane8 = threadIdx.x & 7;        // n = lane8>>2, c-quad = lane8&3
    const int grp   = threadIdx.x >> 3;       // 0..127
    const int loff  = lane8 * 4;              // float offset in row-pair
    const int nl    = lane8 >> 2;
    const int c4f   = (lane8 & 3) * 4;
    float* __restrict__ obase = out + (size_t)(n0 + nl) * (DIM * C) + c4f;

    #pragma unroll
    for (int k = 0; k < DIM / GROUPS; ++k) {  // 4 plan entries per group
        const int4 pl = plan[grp + k * GROUPS];
        const int s = pl.x;
        const int e = pl.y;
        float ax = 0.f, ay = 0.f, az = 0.f, aw = 0.f;
        int p = s;
        if (p < e) {
            int4   pd = pdata[p];
            float4 xv = *reinterpret_cast<const float4*>(xs + pd.x + loff);
            float4 yv = *reinterpret_cast<const float4*>(ys + pd.y + loff);
            while (++p < e) {
                // 1-deep pipeline: issue next path's loads before consuming
                const int4   pdn = pdata[p];
                const float4 xvn = *reinterpret_cast<const float4*>(xs + pdn.x + loff);
                const float4 yvn = *reinterpret_cast<const float4*>(ys + pdn.y + loff);
                const float sc = __int_as_float(pd.z);
                ax = fmaf(sc * xv.x, yv.x, ax);
                ay = fmaf(sc * xv.y, yv.y, ay);
                az = fmaf(sc * xv.z, yv.z, az);
                aw = fmaf(sc * xv.w, yv.w, aw);
                pd = pdn; xv = xvn; yv = yvn;
            }
            const float sc = __int_as_float(pd.z);
            ax = fmaf(sc * xv.x, yv.x, ax);
            ay = fmaf(sc * xv.y, yv.y, ay);
            az = fmaf(sc * xv.z, yv.z, az);
            aw = fmaf(sc * xv.w, yv.w, aw);
        }
        *reinterpret_cast<float4*>(obase + pl.z) = make_float4(ax, ay, az, aw);
    }
}

extern "C" void kernel_launch(void* const* d_in, const int* in_sizes, int n_in,
                              void* d_out, int out_size, void* d_ws, size_t ws_size,
                              hipStream_t stream) {
    const float* x     = (const float*)d_in[0];
    const float* y     = (const float*)d_in[1];
    const float* scale = (const float*)d_in[2];
    const int*   i1    = (const int*)d_in[3];
    const int*   i2    = (const int*)d_in[4];
    const int*   io    = (const int*)d_in[5];
    float* out = (float*)d_out;

    const int nnz = in_sizes[2];
    const int N   = in_sizes[0] / (DIM * C);

    int4* plan  = (int4*)d_ws;                       // DIM int4s (8 KiB)
    int4* pdata = (int4*)((char*)d_ws + 8192);       // nnz int4s (64 KiB)

    const int pack_blocks = (nnz + 255) / 256;
    setup_kernel<<<1 + pack_blocks, 256, 0, stream>>>(io, i1, i2, scale, plan, pdata, nnz);

    constexpr size_t lds_bytes = (size_t)2 * LDSF * sizeof(float);  // 128 KiB
    static bool attr_set = false;
    if (!attr_set) {
        (void)hipFuncSetAttribute((const void*)tp_kernel,
                                  hipFuncAttributeMaxDynamicSharedMemorySize,
                                  (int)lds_bytes);
        attr_set = true;
    }
    tp_kernel<<<N / NPB, TPB, lds_bytes, stream>>>(x, y, plan, pdata, out);
}

// Round 6
// 101.967 us; speedup vs baseline: 1.2042x; 1.0155x over previous
//
#include <hip/hip_runtime.h>

// Problem constants (match the reference file).
constexpr int DIM = 512;   // irreps dim for x, y, out
constexpr int C   = 16;    // channel multiplicity
constexpr int TPB = 1024;  // threads per block (16 waves)
constexpr int NPB = 2;     // n's (batch rows) per block
constexpr int GROUPS = TPB / 8;            // 128 8-lane groups per block
constexpr int XLDSF = DIM * NPB * C;       // 16384 floats (64 KiB) x staging

// Setup: 5 blocks x 1024 threads.
//   block 0:   start[d] via binary search on sorted index_out (1 per thread);
//              rank d's by (segment length desc, d);
//              plan[rank] = {seg_start, seg_end, d*C, 0}.
//   blocks>=1: pdata[p] = {i1*8 (x LDS float4 base), i2*4 (y global float4
//              row base), scale_bits, 0}.
__global__ __launch_bounds__(1024) void setup_kernel(
    const int* __restrict__ io,
    const int* __restrict__ i1,
    const int* __restrict__ i2,
    const float* __restrict__ scale,
    int4* __restrict__ plan,
    int4* __restrict__ pdata,
    int nnz) {
    if (blockIdx.x == 0) {
        __shared__ int s_start[DIM + 1];
        __shared__ int s_len[DIM];
        const int t = threadIdx.x;
        if (t <= DIM) {
            int lo = 0, hi = nnz;
            while (lo < hi) {
                int mid = (lo + hi) >> 1;
                if (io[mid] < t) lo = mid + 1; else hi = mid;
            }
            s_start[t] = lo;
        }
        __syncthreads();
        if (t < DIM) s_len[t] = s_start[t + 1] - s_start[t];
        __syncthreads();
        if (t < DIM) {
            const int ld = s_len[t];
            int rank = 0;
            #pragma unroll 8
            for (int j = 0; j < DIM; ++j) {
                const int lj = s_len[j];
                rank += (lj > ld) || (lj == ld && j < t);
            }
            plan[rank] = make_int4(s_start[t], s_start[t + 1], t * C, 0);
        }
    } else {
        const int p = (blockIdx.x - 1) * 1024 + threadIdx.x;
        if (p < nnz)
            pdata[p] = make_int4(i1[p] * 8, i2[p] * 4, __float_as_int(scale[p]), 0);
    }
}

// One block per PAIR of n. x staged in LDS as X[a][n2][c] (row-pair = 128 B,
// 128 B aligned -> 8-lane groups span all 32 banks: conflict-free-by-
// construction for random rows; proven 3M conflict cycles in R5). y gathered
// straight from global: working set 32 KiB/block * 2 blocks/CU * 32 CU =
// 2 MiB/XCD < 4 MiB L2. 64 KiB LDS -> 2 blocks/CU so one block's gather
// overlaps the other's staging. Balanced plan; 2-deep software pipeline.
__global__ __launch_bounds__(TPB) void tp_kernel(
    const float* __restrict__ x, const float* __restrict__ y,
    const int4* __restrict__ plan,
    const int4* __restrict__ pdata,
    float* __restrict__ out) {
    __shared__ float xs[XLDSF];               // 64 KiB
    float4* xs4 = reinterpret_cast<float4*>(xs);

    const int n0 = blockIdx.x * NPB;
    const float4* __restrict__ xg = reinterpret_cast<const float4*>(x);
    const float4* __restrict__ yg = reinterpret_cast<const float4*>(y);

    // Stage x: LDS float4-slot s <-> (a = s>>3, n = (s>>2)&1, cq = s&3).
    // Global float4 index = (n0+n)*2048 + a*4 + cq. 64 B-chunk coalesced.
    #pragma unroll
    for (int s = threadIdx.x; s < XLDSF / 4; s += TPB) {
        const int a = s >> 3, n = (s >> 2) & 1, cq = s & 3;
        xs4[s] = xg[(size_t)(n0 + n) * (DIM * C / 4) + a * 4 + cq];
    }
    __syncthreads();

    const int lane8 = threadIdx.x & 7;        // n = lane8>>2, c-quad = lane8&3
    const int grp   = threadIdx.x >> 3;       // 0..127
    const int nl    = lane8 >> 2;
    const int cq    = lane8 & 3;
    // y: lane's float4 slot within a row = cq; row base added per path.
    const float4* __restrict__ yrow = yg + (size_t)(n0 + nl) * (DIM * C / 4) + cq;
    float* __restrict__ obase = out + (size_t)(n0 + nl) * (DIM * C) + cq * 4;

    #pragma unroll
    for (int k = 0; k < DIM / GROUPS; ++k) {  // 4 plan entries per group
        const int4 pl = plan[grp + k * GROUPS];
        const int s = pl.x;
        const int e = pl.y;
        float ax = 0.f, ay = 0.f, az = 0.f, aw = 0.f;
        if (s < e) {
            const int last = e - 1;
            int4   pd0 = pdata[s];
            int4   pd1 = pdata[s + 1 < last ? s + 1 : last];
            float4 yv0 = yrow[pd0.y];
            float4 yv1 = yrow[pd1.y];
            float4 xv0 = xs4[pd0.x + lane8];
            float4 xv1 = xs4[pd1.x + lane8];
            for (int p = s; p < e; ++p) {
                const int    pn  = p + 2 < last ? p + 2 : last;
                const int4   pd2 = pdata[pn];
                const float4 yv2 = yrow[pd2.y];
                const float4 xv2 = xs4[pd2.x + lane8];
                const float  sc  = __int_as_float(pd0.z);
                ax = fmaf(sc * xv0.x, yv0.x, ax);
                ay = fmaf(sc * xv0.y, yv0.y, ay);
                az = fmaf(sc * xv0.z, yv0.z, az);
                aw = fmaf(sc * xv0.w, yv0.w, aw);
                pd0 = pd1; pd1 = pd2;
                xv0 = xv1; xv1 = xv2;
                yv0 = yv1; yv1 = yv2;
            }
        }
        *reinterpret_cast<float4*>(obase + pl.z) = make_float4(ax, ay, az, aw);
    }
}

extern "C" void kernel_launch(void* const* d_in, const int* in_sizes, int n_in,
                              void* d_out, int out_size, void* d_ws, size_t ws_size,
                              hipStream_t stream) {
    const float* x     = (const float*)d_in[0];
    const float* y     = (const float*)d_in[1];
    const float* scale = (const float*)d_in[2];
    const int*   i1    = (const int*)d_in[3];
    const int*   i2    = (const int*)d_in[4];
    const int*   io    = (const int*)d_in[5];
    float* out = (float*)d_out;

    const int nnz = in_sizes[2];
    const int N   = in_sizes[0] / (DIM * C);

    int4* plan  = (int4*)d_ws;                       // DIM int4s (8 KiB)
    int4* pdata = (int4*)((char*)d_ws + 8192);       // nnz int4s (64 KiB)

    const int pack_blocks = (nnz + 1023) / 1024;
    setup_kernel<<<1 + pack_blocks, 1024, 0, stream>>>(io, i1, i2, scale, plan, pdata, nnz);
    tp_kernel<<<N / NPB, TPB, 0, stream>>>(x, y, plan, pdata, out);
}

// Round 7
// 81.413 us; speedup vs baseline: 1.5082x; 1.2525x over previous
//
#include <hip/hip_runtime.h>

// Problem constants (match the reference file).
constexpr int DIM = 512;   // irreps dim for x, y, out
constexpr int C   = 16;    // channel multiplicity
constexpr int TPB = 1024;  // threads per block (16 waves)
constexpr int STRIDE = 20; // floats per LDS row slot (80 B: 64 B data + 16 B pad)
constexpr int LDSF = DIM * STRIDE;     // 10240 floats = 40 KiB per array
constexpr int GROUPS = TPB / 4;        // 256 4-lane groups per block

// Setup: block 0 builds the balanced plan; blocks >=1 pack pdata.
//   plan[rank] = {seg_start, seg_end, d*C, 0}, ranks ordered by seg length
//   desc (ties by d).  pdata[p] = {i1*STRIDE, i2*STRIDE, scale_bits, 0}
//   (float offsets of rows in the padded LDS layout).
__global__ __launch_bounds__(1024) void setup_kernel(
    const int* __restrict__ io,
    const int* __restrict__ i1,
    const int* __restrict__ i2,
    const float* __restrict__ scale,
    int4* __restrict__ plan,
    int4* __restrict__ pdata,
    int nnz) {
    if (blockIdx.x == 0) {
        __shared__ int s_start[DIM + 1];
        __shared__ int s_len[DIM];
        const int t = threadIdx.x;
        if (t <= DIM) {
            int lo = 0, hi = nnz;
            while (lo < hi) {
                int mid = (lo + hi) >> 1;
                if (io[mid] < t) lo = mid + 1; else hi = mid;
            }
            s_start[t] = lo;
        }
        __syncthreads();
        if (t < DIM) s_len[t] = s_start[t + 1] - s_start[t];
        __syncthreads();
        if (t < DIM) {
            const int ld = s_len[t];
            int rank = 0;
            #pragma unroll 8
            for (int j = 0; j < DIM; ++j) {
                const int lj = s_len[j];
                rank += (lj > ld) || (lj == ld && j < t);
            }
            plan[rank] = make_int4(s_start[t], s_start[t + 1], t * C, 0);
        }
    } else {
        const int p = (blockIdx.x - 1) * 1024 + threadIdx.x;
        if (p < nnz)
            pdata[p] = make_int4(i1[p] * STRIDE, i2[p] * STRIDE,
                                 __float_as_int(scale[p]), 0);
    }
}

// One block per n.  x-row and y-row staged in LDS with 80 B row stride:
// row a starts at bank (20a)%32, cycling all 8 4-bank offsets -> staging
// writes exactly conflict-free; random gather reads get rotated 16-bank
// windows (~1.45x floor instead of R4's pile-up).  80 KiB LDS -> 2 blocks/CU,
// 32 waves/CU: one block's gather overlaps the other's staging via TLP.
// 4-lane groups own output d's; serpentine rank pairing balances total work
// per group.  2-deep software pipeline.  No atomics.
__global__ __launch_bounds__(TPB) void tp_kernel(
    const float* __restrict__ x, const float* __restrict__ y,
    const int4* __restrict__ plan,
    const int4* __restrict__ pdata,
    float* __restrict__ out) {
    extern __shared__ float lds[];
    float* xs = lds;            // LDSF floats (40 KiB)
    float* ys = lds + LDSF;     // LDSF floats (40 KiB)
    float4* xs4 = reinterpret_cast<float4*>(xs);
    float4* ys4 = reinterpret_cast<float4*>(ys);

    const int n = blockIdx.x;
    const float4* __restrict__ xg = reinterpret_cast<const float4*>(x) + (size_t)n * (DIM * C / 4);
    const float4* __restrict__ yg = reinterpret_cast<const float4*>(y) + (size_t)n * (DIM * C / 4);

    // Stage: global float4 s <-> (a = s>>2, q = s&3); LDS float4 slot = a*5+q
    // (row stride 20 floats = 5 float4s).  Reads coalesced; writes hit each
    // bank exactly 8 times per wave (verified: {20a%32, a=0..15} covers all
    // 8 offsets twice).
    #pragma unroll
    for (int s = threadIdx.x; s < DIM * 4; s += TPB) {   // 2048 float4s, 2 iters
        const int slot = (s >> 2) * 5 + (s & 3);
        xs4[slot] = xg[s];
        ys4[slot] = yg[s];
    }
    __syncthreads();

    const int l4  = threadIdx.x & 3;          // c-quad lane
    const int grp = threadIdx.x >> 2;         // 0..255
    const int c4f = l4 * 4;                   // float offset within row
    float* __restrict__ obase = out + (size_t)n * (DIM * C) + c4f;

    #pragma unroll
    for (int k = 0; k < 2; ++k) {
        // serpentine: group g takes rank g and rank DIM-1-g -> near-constant
        // total paths per group.
        const int4 pl = plan[k ? (DIM - 1 - grp) : grp];
        const int s = pl.x;
        const int e = pl.y;
        float ax = 0.f, ay = 0.f, az = 0.f, aw = 0.f;
        if (s < e) {
            const int last = e - 1;
            int4   pd0 = pdata[s];
            int4   pd1 = pdata[s + 1 < last ? s + 1 : last];
            float4 xv0 = *reinterpret_cast<const float4*>(xs + pd0.x + c4f);
            float4 yv0 = *reinterpret_cast<const float4*>(ys + pd0.y + c4f);
            float4 xv1 = *reinterpret_cast<const float4*>(xs + pd1.x + c4f);
            float4 yv1 = *reinterpret_cast<const float4*>(ys + pd1.y + c4f);
            for (int p = s; p < e; ++p) {
                const int    pn  = p + 2 < last ? p + 2 : last;
                const int4   pd2 = pdata[pn];
                const float4 xv2 = *reinterpret_cast<const float4*>(xs + pd2.x + c4f);
                const float4 yv2 = *reinterpret_cast<const float4*>(ys + pd2.y + c4f);
                const float  sc  = __int_as_float(pd0.z);
                ax = fmaf(sc * xv0.x, yv0.x, ax);
                ay = fmaf(sc * xv0.y, yv0.y, ay);
                az = fmaf(sc * xv0.z, yv0.z, az);
                aw = fmaf(sc * xv0.w, yv0.w, aw);
                pd0 = pd1; pd1 = pd2;
                xv0 = xv1; xv1 = xv2;
                yv0 = yv1; yv1 = yv2;
            }
        }
        *reinterpret_cast<float4*>(obase + pl.z) = make_float4(ax, ay, az, aw);
    }
}

extern "C" void kernel_launch(void* const* d_in, const int* in_sizes, int n_in,
                              void* d_out, int out_size, void* d_ws, size_t ws_size,
                              hipStream_t stream) {
    const float* x     = (const float*)d_in[0];
    const float* y     = (const float*)d_in[1];
    const float* scale = (const float*)d_in[2];
    const int*   i1    = (const int*)d_in[3];
    const int*   i2    = (const int*)d_in[4];
    const int*   io    = (const int*)d_in[5];
    float* out = (float*)d_out;

    const int nnz = in_sizes[2];
    const int N   = in_sizes[0] / (DIM * C);

    int4* plan  = (int4*)d_ws;                       // DIM int4s (8 KiB)
    int4* pdata = (int4*)((char*)d_ws + 8192);       // nnz int4s (64 KiB)

    const int pack_blocks = (nnz + 1023) / 1024;
    setup_kernel<<<1 + pack_blocks, 1024, 0, stream>>>(io, i1, i2, scale, plan, pdata, nnz);

    constexpr size_t lds_bytes = (size_t)2 * LDSF * sizeof(float);  // 80 KiB
    (void)hipFuncSetAttribute((const void*)tp_kernel,
                              hipFuncAttributeMaxDynamicSharedMemorySize,
                              (int)lds_bytes);
    tp_kernel<<<N, TPB, lds_bytes, stream>>>(x, y, plan, pdata, out);
}

// Round 8
// 80.295 us; speedup vs baseline: 1.5292x; 1.0139x over previous
//
#include <hip/hip_runtime.h>

// Problem constants (match the reference file).
constexpr int DIM = 512;   // irreps dim for x, y, out
constexpr int C   = 16;    // channel multiplicity
constexpr int TPB = 1024;  // threads per block (16 waves)
constexpr int STRIDE = 20; // floats per LDS row slot (80 B: 64 B data + 16 B pad)
constexpr int LDSF = DIM * STRIDE;     // 10240 floats = 40 KiB per array

// Setup: block 0 builds the balanced plan; blocks >=1 pack pdata.
//   plan[rank] = {seg_start, seg_end, d*C, 0}, ranks ordered by seg length
//   desc (ties by d).  pdata[p] = {i1*STRIDE, i2*STRIDE, scale_bits, 0}.
__global__ __launch_bounds__(1024) void setup_kernel(
    const int* __restrict__ io,
    const int* __restrict__ i1,
    const int* __restrict__ i2,
    const float* __restrict__ scale,
    int4* __restrict__ plan,
    int4* __restrict__ pdata,
    int nnz) {
    if (blockIdx.x == 0) {
        __shared__ int s_start[DIM + 1];
        __shared__ int s_len[DIM];
        const int t = threadIdx.x;
        if (t <= DIM) {
            int lo = 0, hi = nnz;
            while (lo < hi) {
                int mid = (lo + hi) >> 1;
                if (io[mid] < t) lo = mid + 1; else hi = mid;
            }
            s_start[t] = lo;
        }
        __syncthreads();
        if (t < DIM) s_len[t] = s_start[t + 1] - s_start[t];
        __syncthreads();
        if (t < DIM) {
            const int ld = s_len[t];
            int rank = 0;
            #pragma unroll 8
            for (int j = 0; j < DIM; ++j) {
                const int lj = s_len[j];
                rank += (lj > ld) || (lj == ld && j < t);
            }
            plan[rank] = make_int4(s_start[t], s_start[t + 1], t * C, 0);
        }
    } else {
        const int p = (blockIdx.x - 1) * 1024 + threadIdx.x;
        if (p < nnz)
            pdata[p] = make_int4(i1[p] * STRIDE, i2[p] * STRIDE,
                                 __float_as_int(scale[p]), 0);
    }
}

// One block per n.  R7's proven layout: 80 B LDS row stride (staging writes
// conflict-free, random reads ~1.56x b128 floor), balanced serpentine plan,
// 2 blocks/CU.  R8 change: kill exposed latency.  plan + head pdata loads
// hoisted BEFORE staging (hide under staging's global loads); inner loop
// prefetches pdata at depth 4 and LDS at depth 2; chain B's head ds_reads
// issued before chain A's store.  No atomics.
__global__ __launch_bounds__(TPB) void tp_kernel(
    const float* __restrict__ x, const float* __restrict__ y,
    const int4* __restrict__ plan,
    const int4* __restrict__ pdata,
    float* __restrict__ out) {
    extern __shared__ float lds[];
    float* xs = lds;            // LDSF floats (40 KiB)
    float* ys = lds + LDSF;     // LDSF floats (40 KiB)
    float4* xs4 = reinterpret_cast<float4*>(xs);
    float4* ys4 = reinterpret_cast<float4*>(ys);

    const int n = blockIdx.x;
    const float4* __restrict__ xg = reinterpret_cast<const float4*>(x) + (size_t)n * (DIM * C / 4);
    const float4* __restrict__ yg = reinterpret_cast<const float4*>(y) + (size_t)n * (DIM * C / 4);

    const int l4  = threadIdx.x & 3;          // c-quad lane
    const int grp = threadIdx.x >> 2;         // 0..255
    const int c4f = l4 * 4;                   // float offset within row

    // ---- hoisted prologue: plan + first two pdata of each chain ----
    const int4 plA = plan[grp];
    const int4 plB = plan[DIM - 1 - grp];
    const int sA = plA.x, eA = plA.y, lastA = eA - 1;
    const int sB = plB.x, eB = plB.y, lastB = eB - 1;
    int4 qA0, qA1, qB0, qB1;
    if (sA < eA) {
        qA0 = pdata[sA];
        qA1 = pdata[sA + 1 < lastA ? sA + 1 : lastA];
    }
    if (sB < eB) {
        qB0 = pdata[sB];
        qB1 = pdata[sB + 1 < lastB ? sB + 1 : lastB];
    }

    // ---- stage x,y rows into padded LDS (conflict-free writes) ----
    #pragma unroll
    for (int s = threadIdx.x; s < DIM * 4; s += TPB) {   // 2048 float4s, 2 iters
        const int slot = (s >> 2) * 5 + (s & 3);
        xs4[slot] = xg[s];
        ys4[slot] = yg[s];
    }
    __syncthreads();

    float* __restrict__ obase = out + (size_t)n * (DIM * C) + c4f;

    // ---- chain A ----
    float aAx = 0.f, aAy = 0.f, aAz = 0.f, aAw = 0.f;
    if (sA < eA) {
        float4 v0x = *reinterpret_cast<const float4*>(xs + qA0.x + c4f);
        float4 v0y = *reinterpret_cast<const float4*>(ys + qA0.y + c4f);
        float4 v1x = *reinterpret_cast<const float4*>(xs + qA1.x + c4f);
        float4 v1y = *reinterpret_cast<const float4*>(ys + qA1.y + c4f);
        float s0 = __int_as_float(qA0.z);
        float s1 = __int_as_float(qA1.z);
        int4 q2 = pdata[sA + 2 < lastA ? sA + 2 : lastA];
        int4 q3 = pdata[sA + 3 < lastA ? sA + 3 : lastA];
        for (int p = sA; p < eA; ++p) {
            const int4 q4 = pdata[p + 4 < lastA ? p + 4 : lastA];
            const float4 v2x = *reinterpret_cast<const float4*>(xs + q2.x + c4f);
            const float4 v2y = *reinterpret_cast<const float4*>(ys + q2.y + c4f);
            aAx = fmaf(s0 * v0x.x, v0y.x, aAx);
            aAy = fmaf(s0 * v0x.y, v0y.y, aAy);
            aAz = fmaf(s0 * v0x.z, v0y.z, aAz);
            aAw = fmaf(s0 * v0x.w, v0y.w, aAw);
            s0 = s1; s1 = __int_as_float(q2.z);
            q2 = q3; q3 = q4;
            v0x = v1x; v0y = v1y; v1x = v2x; v1y = v2y;
        }
    }

    // ---- chain B prologue (ds_reads issued before A's store) ----
    float4 w0x, w0y, w1x, w1y;
    int4 r2, r3;
    float t0 = 0.f, t1 = 0.f;
    if (sB < eB) {
        w0x = *reinterpret_cast<const float4*>(xs + qB0.x + c4f);
        w0y = *reinterpret_cast<const float4*>(ys + qB0.y + c4f);
        w1x = *reinterpret_cast<const float4*>(xs + qB1.x + c4f);
        w1y = *reinterpret_cast<const float4*>(ys + qB1.y + c4f);
        t0 = __int_as_float(qB0.z);
        t1 = __int_as_float(qB1.z);
        r2 = pdata[sB + 2 < lastB ? sB + 2 : lastB];
        r3 = pdata[sB + 3 < lastB ? sB + 3 : lastB];
    }

    *reinterpret_cast<float4*>(obase + plA.z) = make_float4(aAx, aAy, aAz, aAw);

    // ---- chain B ----
    float aBx = 0.f, aBy = 0.f, aBz = 0.f, aBw = 0.f;
    if (sB < eB) {
        for (int p = sB; p < eB; ++p) {
            const int4 r4 = pdata[p + 4 < lastB ? p + 4 : lastB];
            const float4 v2x = *reinterpret_cast<const float4*>(xs + r2.x + c4f);
            const float4 v2y = *reinterpret_cast<const float4*>(ys + r2.y + c4f);
            aBx = fmaf(t0 * w0x.x, w0y.x, aBx);
            aBy = fmaf(t0 * w0x.y, w0y.y, aBy);
            aBz = fmaf(t0 * w0x.z, w0y.z, aBz);
            aBw = fmaf(t0 * w0x.w, w0y.w, aBw);
            t0 = t1; t1 = __int_as_float(r2.z);
            r2 = r3; r3 = r4;
            w0x = w1x; w0y = w1y; w1x = v2x; w1y = v2y;
        }
    }
    *reinterpret_cast<float4*>(obase + plB.z) = make_float4(aBx, aBy, aBz, aBw);
}

extern "C" void kernel_launch(void* const* d_in, const int* in_sizes, int n_in,
                              void* d_out, int out_size, void* d_ws, size_t ws_size,
                              hipStream_t stream) {
    const float* x     = (const float*)d_in[0];
    const float* y     = (const float*)d_in[1];
    const float* scale = (const float*)d_in[2];
    const int*   i1    = (const int*)d_in[3];
    const int*   i2    = (const int*)d_in[4];
    const int*   io    = (const int*)d_in[5];
    float* out = (float*)d_out;

    const int nnz = in_sizes[2];
    const int N   = in_sizes[0] / (DIM * C);

    int4* plan  = (int4*)d_ws;                       // DIM int4s (8 KiB)
    int4* pdata = (int4*)((char*)d_ws + 8192);       // nnz int4s (64 KiB)

    const int pack_blocks = (nnz + 1023) / 1024;
    setup_kernel<<<1 + pack_blocks, 1024, 0, stream>>>(io, i1, i2, scale, plan, pdata, nnz);

    constexpr size_t lds_bytes = (size_t)2 * LDSF * sizeof(float);  // 80 KiB
    (void)hipFuncSetAttribute((const void*)tp_kernel,
                              hipFuncAttributeMaxDynamicSharedMemorySize,
                              (int)lds_bytes);
    tp_kernel<<<N, TPB, lds_bytes, stream>>>(x, y, plan, pdata, out);
}

// Round 9
// 74.314 us; speedup vs baseline: 1.6522x; 1.0805x over previous
//
#include <hip/hip_runtime.h>

// Problem constants (match the reference file).
constexpr int DIM = 512;   // irreps dim for x, y, out
constexpr int C   = 16;    // channel multiplicity
constexpr int TPB = 1024;  // threads per block (16 waves)
constexpr int STRIDE = 20; // floats per LDS row slot (80 B: 64 B data + 16 B pad)
constexpr int BUF = DIM * STRIDE;      // 10240 floats = 40 KiB per array
constexpr int NBLK = 256;              // persistent blocks (1 per CU)

// Setup: block 0 builds the balanced plan; blocks >=1 pack pdata.
//   plan[rank] = {seg_start, seg_end, d*C, 0}, ranks ordered by seg length
//   desc (ties by d).  pdata[p] = {i1*STRIDE, i2*STRIDE, scale_bits, 0}.
__global__ __launch_bounds__(1024) void setup_kernel(
    const int* __restrict__ io,
    const int* __restrict__ i1,
    const int* __restrict__ i2,
    const float* __restrict__ scale,
    int4* __restrict__ plan,
    int4* __restrict__ pdata,
    int nnz) {
    if (blockIdx.x == 0) {
        __shared__ int s_start[DIM + 1];
        __shared__ int s_len[DIM];
        const int t = threadIdx.x;
        if (t <= DIM) {
            int lo = 0, hi = nnz;
            while (lo < hi) {
                int mid = (lo + hi) >> 1;
                if (io[mid] < t) lo = mid + 1; else hi = mid;
            }
            s_start[t] = lo;
        }
        __syncthreads();
        if (t < DIM) s_len[t] = s_start[t + 1] - s_start[t];
        __syncthreads();
        if (t < DIM) {
            const int ld = s_len[t];
            int rank = 0;
            #pragma unroll 8
            for (int j = 0; j < DIM; ++j) {
                const int lj = s_len[j];
                rank += (lj > ld) || (lj == ld && j < t);
            }
            plan[rank] = make_int4(s_start[t], s_start[t + 1], t * C, 0);
        }
    } else {
        const int p = (blockIdx.x - 1) * 1024 + threadIdx.x;
        if (p < nnz)
            pdata[p] = make_int4(i1[p] * STRIDE, i2[p] * STRIDE,
                                 __float_as_int(scale[p]), 0);
    }
}

// Persistent kernel: 256 blocks (1/CU), each processes N/256 batch rows with
// a double-buffered LDS pipeline (2 x 80 KiB = 160 KiB = full CU LDS).
// Per round: issue next row-pair's global loads into regs -> gather current
// buffer (proven stride-20 layout: staging writes conflict-free, random
// reads ~1.5x b128 floor; balanced serpentine plan) -> ds_write regs into
// other buffer -> store out -> one barrier.  HBM latency of stage r+1 hides
// under gather r.  plan + segment-head pdata live in persistent registers
// (identical every round).  No atomics.
__global__ __launch_bounds__(TPB) void tp_kernel(
    const float* __restrict__ x, const float* __restrict__ y,
    const int4* __restrict__ plan,
    const int4* __restrict__ pdata,
    float* __restrict__ out,
    int N) {
    extern __shared__ float lds[];

    const int nb  = blockIdx.x;
    const int l4  = threadIdx.x & 3;          // c-quad lane
    const int grp = threadIdx.x >> 2;         // 0..255
    const int c4f = l4 * 4;                   // float offset within row

    // ---- persistent per-thread plan state (same every round) ----
    const int4 plA = plan[grp];
    const int4 plB = plan[DIM - 1 - grp];
    const int sA = plA.x, eA = plA.y, lastA = eA - 1;
    const int sB = plB.x, eB = plB.y, lastB = eB - 1;
    int4 qA0, qA1, qB0, qB1;                  // segment heads, persistent
    if (sA < eA) {
        qA0 = pdata[sA];
        qA1 = pdata[sA + 1 < lastA ? sA + 1 : lastA];
    }
    if (sB < eB) {
        qB0 = pdata[sB];
        qB1 = pdata[sB + 1 < lastB ? sB + 1 : lastB];
    }

    const float4* __restrict__ xg = reinterpret_cast<const float4*>(x);
    const float4* __restrict__ yg = reinterpret_cast<const float4*>(y);
    const int t0 = threadIdx.x;
    const int t1 = threadIdx.x + TPB;
    const int slot0 = (t0 >> 2) * 5 + (t0 & 3);   // padded LDS float4 slot
    const int slot1 = (t1 >> 2) * 5 + (t1 & 3);

    // ---- prologue: stage first row into buffer 0 ----
    if (nb < N) {
        const size_t gb = (size_t)nb * (DIM * C / 4);
        const float4 a0 = xg[gb + t0], a1 = xg[gb + t1];
        const float4 b0 = yg[gb + t0], b1 = yg[gb + t1];
        float4* xs4 = reinterpret_cast<float4*>(lds);
        float4* ys4 = reinterpret_cast<float4*>(lds + BUF);
        xs4[slot0] = a0; xs4[slot1] = a1;
        ys4[slot0] = b0; ys4[slot1] = b1;
    }
    __syncthreads();

    int k = 0;
    for (int n = nb; n < N; n += NBLK) {
        float* xs = lds + k * (2 * BUF);
        float* ys = xs + BUF;

        // ---- issue next round's staging loads (latency hides under gather) ----
        const bool more = (n + NBLK) < N;
        float4 a0, a1, b0, b1;
        if (more) {
            const size_t gb = (size_t)(n + NBLK) * (DIM * C / 4);
            a0 = xg[gb + t0]; a1 = xg[gb + t1];
            b0 = yg[gb + t0]; b1 = yg[gb + t1];
        }

        // ---- chain A ----
        float aAx = 0.f, aAy = 0.f, aAz = 0.f, aAw = 0.f;
        if (sA < eA) {
            float4 v0x = *reinterpret_cast<const float4*>(xs + qA0.x + c4f);
            float4 v0y = *reinterpret_cast<const float4*>(ys + qA0.y + c4f);
            float4 v1x = *reinterpret_cast<const float4*>(xs + qA1.x + c4f);
            float4 v1y = *reinterpret_cast<const float4*>(ys + qA1.y + c4f);
            float s0 = __int_as_float(qA0.z);
            float s1 = __int_as_float(qA1.z);
            int4 q2 = pdata[sA + 2 < lastA ? sA + 2 : lastA];
            int4 q3 = pdata[sA + 3 < lastA ? sA + 3 : lastA];
            for (int p = sA; p < eA; ++p) {
                const int4 q4 = pdata[p + 4 < lastA ? p + 4 : lastA];
                const float4 v2x = *reinterpret_cast<const float4*>(xs + q2.x + c4f);
                const float4 v2y = *reinterpret_cast<const float4*>(ys + q2.y + c4f);
                aAx = fmaf(s0 * v0x.x, v0y.x, aAx);
                aAy = fmaf(s0 * v0x.y, v0y.y, aAy);
                aAz = fmaf(s0 * v0x.z, v0y.z, aAz);
                aAw = fmaf(s0 * v0x.w, v0y.w, aAw);
                s0 = s1; s1 = __int_as_float(q2.z);
                q2 = q3; q3 = q4;
                v0x = v1x; v0y = v1y; v1x = v2x; v1y = v2y;
            }
        }

        // ---- chain B ----
        float aBx = 0.f, aBy = 0.f, aBz = 0.f, aBw = 0.f;
        if (sB < eB) {
            float4 w0x = *reinterpret_cast<const float4*>(xs + qB0.x + c4f);
            float4 w0y = *reinterpret_cast<const float4*>(ys + qB0.y + c4f);
            float4 w1x = *reinterpret_cast<const float4*>(xs + qB1.x + c4f);
            float4 w1y = *reinterpret_cast<const float4*>(ys + qB1.y + c4f);
            float t0s = __int_as_float(qB0.z);
            float t1s = __int_as_float(qB1.z);
            int4 r2 = pdata[sB + 2 < lastB ? sB + 2 : lastB];
            int4 r3 = pdata[sB + 3 < lastB ? sB + 3 : lastB];
            for (int p = sB; p < eB; ++p) {
                const int4 r4 = pdata[p + 4 < lastB ? p + 4 : lastB];
                const float4 v2x = *reinterpret_cast<const float4*>(xs + r2.x + c4f);
                const float4 v2y = *reinterpret_cast<const float4*>(ys + r2.y + c4f);
                aBx = fmaf(t0s * w0x.x, w0y.x, aBx);
                aBy = fmaf(t0s * w0x.y, w0y.y, aBy);
                aBz = fmaf(t0s * w0x.z, w0y.z, aBz);
                aBw = fmaf(t0s * w0x.w, w0y.w, aBw);
                t0s = t1s; t1s = __int_as_float(r2.z);
                r2 = r3; r3 = r4;
                w0x = w1x; w0y = w1y; w1x = v2x; w1y = v2y;
            }
        }

        // ---- write staged regs into the other buffer (waits staging loads) ----
        if (more) {
            float* nbuf = lds + (k ^ 1) * (2 * BUF);
            float4* nx4 = reinterpret_cast<float4*>(nbuf);
            float4* ny4 = reinterpret_cast<float4*>(nbuf + BUF);
            nx4[slot0] = a0; nx4[slot1] = a1;
            ny4[slot0] = b0; ny4[slot1] = b1;
        }

        // ---- store outputs (fire-and-forget), then barrier ----
        float* obase = out + (size_t)n * (DIM * C) + c4f;
        *reinterpret_cast<float4*>(obase + plA.z) = make_float4(aAx, aAy, aAz, aAw);
        *reinterpret_cast<float4*>(obase + plB.z) = make_float4(aBx, aBy, aBz, aBw);
        __syncthreads();
        k ^= 1;
    }
}

extern "C" void kernel_launch(void* const* d_in, const int* in_sizes, int n_in,
                              void* d_out, int out_size, void* d_ws, size_t ws_size,
                              hipStream_t stream) {
    const float* x     = (const float*)d_in[0];
    const float* y     = (const float*)d_in[1];
    const float* scale = (const float*)d_in[2];
    const int*   i1    = (const int*)d_in[3];
    const int*   i2    = (const int*)d_in[4];
    const int*   io    = (const int*)d_in[5];
    float* out = (float*)d_out;

    const int nnz = in_sizes[2];
    const int N   = in_sizes[0] / (DIM * C);

    int4* plan  = (int4*)d_ws;                       // DIM int4s (8 KiB)
    int4* pdata = (int4*)((char*)d_ws + 8192);       // nnz int4s (64 KiB)

    const int pack_blocks = (nnz + 1023) / 1024;
    setup_kernel<<<1 + pack_blocks, 1024, 0, stream>>>(io, i1, i2, scale, plan, pdata, nnz);

    constexpr size_t lds_bytes = (size_t)4 * BUF * sizeof(float);  // 160 KiB
    (void)hipFuncSetAttribute((const void*)tp_kernel,
                              hipFuncAttributeMaxDynamicSharedMemorySize,
                              (int)lds_bytes);
    tp_kernel<<<NBLK, TPB, lds_bytes, stream>>>(x, y, plan, pdata, out, N);
}